// Round 6
// baseline (405.778 us; speedup 1.0000x reference)
//
#include <hip/hip_runtime.h>

#define BINS 10
#define NBUF 64        // accumulation buffers per block: 4 waves * 16
#define BUFSTRIDE 21   // floats; 21 coprime with 32 banks -> spread bank offsets

// GHM-C, momentum=0, single streaming pass.
// loss = (1/n_nonempty) * sum_b ( bce_sum[b] / count[b] )   (tot cancels)
// t in {0,1}: q = (1-2t)*p  =>  g = sigmoid(q) = rcp(1+exp(-q)), bce = softplus(q).
//
// R5 redesign: direct per-bin accumulation via LDS float atomics (ds_add_f32).
// R1-R4's 20-register cumulative compare chains (60 VALU/elem) forced the
// scheduler into a minimal-pressure serial schedule (VGPR 28-36 every round,
// dur pinned ~105us, all pipes idle => latency-stall-bound). Now ~16 VALU/elem,
// scatter on the LDS pipe, no accumulator registers -> scheduler can keep the
// unroll-2's 6 float4 loads actually in flight.
// Invalid elements (w=0) add 0.0f to sum AND count -> zero masking ops.
//
// ws: float part[20][grid]; rows 0..9 = per-bin bce sums, 10..19 = counts.

__device__ __forceinline__ void ghmc_elem(float pk, float tk, float wk,
                                          float* __restrict__ hb) {
    const float NL2E = -1.44269504f;   // -log2(e)
    float m  = fmaf(-2.0f, tk, 1.0f);              // +1 / -1
    float q  = m * pk;
    float e2 = __expf(-q);                          // exp(-q)  (mul + v_exp)
    float g  = __builtin_amdgcn_rcpf(1.0f + e2);    // sigmoid(q), 1-ulp rcp
    int   bi = (int)(g * 10.0f);                    // g>=0 -> trunc == floor
    bi = bi > (BINS - 1) ? (BINS - 1) : bi;
    float u  = __expf(-fabsf(q));                   // exp(-|q|) (abs is a modifier)
    float bce = fmaf(__logf(1.0f + u), 1.0f, fmaxf(q, 0.0f));  // softplus(q)
    atomicAdd(&hb[bi], bce * wk);                   // ds_add_f32 (no return)
    atomicAdd(&hb[bi + BINS], wk);                  // same vaddr, offset:+40
    (void)NL2E;
}

__global__ __launch_bounds__(256) void ghmc_main(
    const float* __restrict__ pred, const float* __restrict__ targ,
    const float* __restrict__ lw, float* __restrict__ part, int n, int grid) {

    __shared__ float h[NBUF * BUFSTRIDE];
    for (int i = threadIdx.x; i < NBUF * BUFSTRIDE; i += 256) h[i] = 0.0f;
    __syncthreads();

    // 4 lanes share a buffer: lanes l, l+16, l+32, l+48 of a wave
    const int buf = ((threadIdx.x >> 6) << 4) | (threadIdx.x & 15);
    float* hb = &h[buf * BUFSTRIDE];

    const int tid    = blockIdx.x * blockDim.x + threadIdx.x;
    const int stride = grid * blockDim.x;
    const int nvec   = n >> 2;

    const float4* p4 = (const float4*)pred;
    const float4* t4 = (const float4*)targ;
    const float4* w4 = (const float4*)lw;

    int i = tid;
    for (; i + stride < nvec; i += 2 * stride) {
        const int i2 = i + stride;
        float4 pA = p4[i],  tA = t4[i],  wA = w4[i];
        float4 pB = p4[i2], tB = t4[i2], wB = w4[i2];
        ghmc_elem(pA.x, tA.x, wA.x, hb);
        ghmc_elem(pA.y, tA.y, wA.y, hb);
        ghmc_elem(pA.z, tA.z, wA.z, hb);
        ghmc_elem(pA.w, tA.w, wA.w, hb);
        ghmc_elem(pB.x, tB.x, wB.x, hb);
        ghmc_elem(pB.y, tB.y, wB.y, hb);
        ghmc_elem(pB.z, tB.z, wB.z, hb);
        ghmc_elem(pB.w, tB.w, wB.w, hb);
    }
    for (; i < nvec; i += stride) {
        float4 p = p4[i], t = t4[i], w = w4[i];
        ghmc_elem(p.x, t.x, w.x, hb);
        ghmc_elem(p.y, t.y, w.y, hb);
        ghmc_elem(p.z, t.z, w.z, hb);
        ghmc_elem(p.w, t.w, w.w, hb);
    }
    {   // scalar tail (n % 4)
        int rem = n & 3;
        if (tid < rem) {
            int idx = (nvec << 2) + tid;
            ghmc_elem(pred[idx], targ[idx], lw[idx], hb);
        }
    }

    __syncthreads();
    // fold 64 buffers -> 20 per-block partials
    if (threadIdx.x < 2 * BINS) {
        float v = 0.0f;
#pragma unroll 8
        for (int k = 0; k < NBUF; ++k) v += h[k * BUFSTRIDE + threadIdx.x];
        part[threadIdx.x * grid + blockIdx.x] = v;
    }
}

__global__ __launch_bounds__(256) void ghmc_fin(
    const float* __restrict__ part, float* __restrict__ out, int grid) {
    __shared__ float rows[2 * BINS];
    __shared__ float wsum[4];
    for (int k = 0; k < 2 * BINS; ++k) {
        float v = 0.0f;
        for (int i = threadIdx.x; i < grid; i += 256) v += part[k * grid + i];
#pragma unroll
        for (int off = 32; off > 0; off >>= 1) v += __shfl_xor(v, off, 64);
        if ((threadIdx.x & 63) == 0) wsum[threadIdx.x >> 6] = v;
        __syncthreads();
        if (threadIdx.x == 0) rows[k] = wsum[0] + wsum[1] + wsum[2] + wsum[3];
        __syncthreads();
    }
    if (threadIdx.x == 0) {
        float acc = 0.0f;
        int   nb  = 0;
#pragma unroll
        for (int b = 0; b < BINS; ++b) {
            float s = rows[b];           // per-bin bce sum (direct, no differencing)
            float c = rows[BINS + b];    // per-bin valid count
            if (c > 0.5f) { nb += 1; acc += s / c; }
        }
        out[0] = (nb > 0) ? (acc / (float)nb) : 0.0f;  // LOSS_WEIGHT = 1
    }
}

extern "C" void kernel_launch(void* const* d_in, const int* in_sizes, int n_in,
                              void* d_out, int out_size, void* d_ws, size_t ws_size,
                              hipStream_t stream) {
    const float* pred = (const float*)d_in[0];
    const float* targ = (const float*)d_in[1];
    const float* lw   = (const float*)d_in[2];
    float* out  = (float*)d_out;
    float* part = (float*)d_ws;
    const int n = in_sizes[0];   // 20,971,520

    int grid = 2048;             // grid-stride; exactly 10 float4 iters/thread
    size_t need = (size_t)grid * 2 * BINS * sizeof(float);
    if (ws_size < need) {
        grid = (int)(ws_size / (2 * BINS * sizeof(float)));
        if (grid < 1) grid = 1;
    }

    ghmc_main<<<grid, 256, 0, stream>>>(pred, targ, lw, part, n, grid);
    ghmc_fin<<<1, 256, 0, stream>>>(part, out, grid);
}